// Round 3
// baseline (25.259 us; speedup 1.0000x reference)
//
#include <hip/hip_runtime.h>
#include <hip/hip_bf16.h>

#define TOKS 2048
#define FEAT 2048
#define NR   128
#define KB   32
#define RB   32
#define TT   32

typedef __attribute__((ext_vector_type(8))) short bf16x8;
typedef __attribute__((ext_vector_type(4))) float f32x4;

__device__ __forceinline__ unsigned short f2bf(float f) {
    unsigned u = __builtin_bit_cast(unsigned, f);
    u += 0x7FFFu + ((u >> 16) & 1u);
    return (unsigned short)(u >> 16);
}

__device__ __forceinline__ bf16x8 pack8(float4 a, float4 b) {
    bf16x8 r;
    r[0] = (short)f2bf(a.x); r[1] = (short)f2bf(a.y);
    r[2] = (short)f2bf(a.z); r[3] = (short)f2bf(a.w);
    r[4] = (short)f2bf(b.x); r[5] = (short)f2bf(b.y);
    r[6] = (short)f2bf(b.z); r[7] = (short)f2bf(b.w);
    return r;
}

// One prep kernel converts BOTH x (4M elems) and values (1M elems) to bf16 in ws.
// Grid = 2048 + 512 blocks of 256 threads, 8 elems/thread.
__global__ __launch_bounds__(256) void prep_kernel(const float* __restrict__ x,
                                                   const float* __restrict__ v,
                                                   unsigned short* __restrict__ xb,
                                                   unsigned short* __restrict__ vb) {
    int bid = blockIdx.x;
    const float* src;
    unsigned short* dst;
    size_t base;
    if (bid < 2048) { src = x; dst = xb; base = ((size_t)bid * 256 + threadIdx.x) * 8; }
    else            { src = v; dst = vb; base = ((size_t)(bid - 2048) * 256 + threadIdx.x) * 8; }
    float4 a = *reinterpret_cast<const float4*>(src + base);
    float4 b = *reinterpret_cast<const float4*>(src + base + 4);
    *reinterpret_cast<bf16x8*>(dst + base) = pack8(a, b);
}

// ---------------- fast path: all-bf16, async LDS staging ----------------
// grid = 64 tg * 4 rg = 256 blocks, 1024 threads (16 waves).
__global__ __launch_bounds__(1024) void bsp3(const unsigned short* __restrict__ xb,
                                             const unsigned short* __restrict__ vb,
                                             const int* __restrict__ cols,
                                             const float* __restrict__ bias,
                                             float* __restrict__ out) {
    __shared__ __align__(16) unsigned short xs[TT * FEAT];   // 128 KiB, swizzled layout

    int bid  = blockIdx.x;
    int xcd  = bid & 7, slot = bid >> 3;
    int tg   = xcd * 8 + (slot >> 2);
    int rg   = slot & 3;
    int tok0 = tg * TT;
    int r0   = rg * RB;
    int tid  = threadIdx.x;
    int wave = tid >> 6;
    int lane = tid & 63;

    // ---- async stage: 32 rows x 4 KiB each, global_load_lds width=16.
    // LDS layout: byte(t, ch) = t*4096 + (ch*16 ^ ((t&7)*16)).
    // global_load_lds writes linearly (uniform base + lane*16), so the swizzle
    // is applied to the per-lane GLOBAL source: ch_src = s*64 + (lane ^ (t&7)).
    #pragma unroll
    for (int i = 0; i < 2; ++i) {
        int t = wave * 2 + i;
        const unsigned short* rowp = xb + (size_t)(tok0 + t) * FEAT;
        int lsw = lane ^ (t & 7);
        #pragma unroll
        for (int s = 0; s < 4; ++s) {
            __builtin_amdgcn_global_load_lds(
                (const __attribute__((address_space(1))) void*)(rowp + (s * 64 + lsw) * 8),
                (__attribute__((address_space(3))) void*)(xs + t * 2048 + s * 512),
                16, 0, 0);
        }
    }

    int n = lane & 15;          // token-in-16 == output i == D col
    int g = lane >> 4;
    int h = g & 1;              // 8-elem half within a 16-wide block
    int q = g >> 1;             // which gathered block of the MFMA pair

    int mrow = n << 12;
    int axor = (n & 7) << 4;

    // prefetch rr=0 fragments under the staging drain
    bf16x8 bfrag[16];
    int aaddr[16];
    {
        int r = r0 + wave * 2;
        int cbase = __builtin_amdgcn_readfirstlane(r) * KB;
        const unsigned short* vbl = vb + ((size_t)r << 13) + (q << 8) + (n << 4) + (h << 3);
        #pragma unroll
        for (int t = 0; t < 16; ++t) {
            bfrag[t] = *reinterpret_cast<const bf16x8*>(vbl + t * 512);
            int c = cols[cbase + 2 * t + q];
            aaddr[t] = mrow + (((c << 5) + (h << 4)) ^ axor);
        }
    }

    __syncthreads();   // compiler emits vmcnt(0) drain here -> staging complete

    #pragma unroll 1
    for (int rr = 0; rr < 2; ++rr) {
        int r = r0 + wave * 2 + rr;
        if (rr > 0) {
            int cbase = __builtin_amdgcn_readfirstlane(r) * KB;
            const unsigned short* vbl = vb + ((size_t)r << 13) + (q << 8) + (n << 4) + (h << 3);
            #pragma unroll
            for (int t = 0; t < 16; ++t) {
                bfrag[t] = *reinterpret_cast<const bf16x8*>(vbl + t * 512);
                int c = cols[cbase + 2 * t + q];
                aaddr[t] = mrow + (((c << 5) + (h << 4)) ^ axor);
            }
        }

        float fb = bias[(r << 4) + n];

        #pragma unroll
        for (int sx = 0; sx < 2; ++sx) {
            const char* xbp = reinterpret_cast<const char*>(xs) + (sx << 16);
            f32x4 acc0 = {0.f, 0.f, 0.f, 0.f};
            f32x4 acc1 = {0.f, 0.f, 0.f, 0.f};
            #pragma unroll
            for (int t = 0; t < 8; ++t) {
                bf16x8 a0 = *reinterpret_cast<const bf16x8*>(xbp + aaddr[2 * t]);
                bf16x8 a1 = *reinterpret_cast<const bf16x8*>(xbp + aaddr[2 * t + 1]);
                acc0 = __builtin_amdgcn_mfma_f32_16x16x32_bf16(a0, bfrag[2 * t],     acc0, 0, 0, 0);
                acc1 = __builtin_amdgcn_mfma_f32_16x16x32_bf16(a1, bfrag[2 * t + 1], acc1, 0, 0, 0);
            }
            int trow = tok0 + (sx << 4) + (g << 2);
            size_t ob = (size_t)trow * 2048 + (r << 4) + n;
            #pragma unroll
            for (int p = 0; p < 4; ++p)
                out[ob + (size_t)p * 2048] = acc0[p] + acc1[p] + fb;
        }
    }
}

// ---------------- fallback (small ws): round-1/2 style, fp32 direct ----------------
__global__ __launch_bounds__(1024, 4) void bsp_fb(const float* __restrict__ x,
                                                  const float* __restrict__ values,
                                                  const int* __restrict__ cols,
                                                  const float* __restrict__ bias,
                                                  float* __restrict__ out) {
    __shared__ __align__(16) unsigned short xs[TT * FEAT];

    int bid  = blockIdx.x;
    int xcd  = bid & 7, slot = bid >> 3;
    int tg   = xcd * 8 + (slot >> 2);
    int rg   = slot & 3;
    int tok0 = tg * TT;
    int r0   = rg * RB;
    int tid  = threadIdx.x;

    {
        int tr = tid >> 8;
        int ch = tid & 255;
        #pragma unroll 2
        for (int it = 0; it < 8; ++it) {
            int t = it * 4 + tr;
            const float4* p = reinterpret_cast<const float4*>(
                x + (size_t)(tok0 + t) * FEAT + ch * 8);
            float4 a = p[0], b = p[1];
            int off = (t << 12) + ((ch << 4) ^ ((t & 7) << 4));
            *reinterpret_cast<bf16x8*>(reinterpret_cast<char*>(xs) + off) = pack8(a, b);
        }
    }
    __syncthreads();

    int wave = tid >> 6;
    int lane = tid & 63;
    int n = lane & 15;
    int g = lane >> 4;
    int h = g & 1;
    int q = g >> 1;
    int mrow = n << 12;
    int axor = (n & 7) << 4;

    #pragma unroll 1
    for (int rr = 0; rr < 2; ++rr) {
        int r = r0 + wave * 2 + rr;
        int cbase = __builtin_amdgcn_readfirstlane(r) * KB;
        bf16x8 bfrag[16];
        int aaddr[16];
        const float* vfl = values + ((size_t)r << 13) + (q << 8) + (n << 4) + (h << 3);
        #pragma unroll
        for (int t = 0; t < 16; ++t) {
            const float4* pv = reinterpret_cast<const float4*>(vfl + t * 512);
            bfrag[t] = pack8(pv[0], pv[1]);
            int c = cols[cbase + 2 * t + q];
            aaddr[t] = mrow + (((c << 5) + (h << 4)) ^ axor);
        }
        float fb = bias[(r << 4) + n];
        #pragma unroll
        for (int sx = 0; sx < 2; ++sx) {
            const char* xbp = reinterpret_cast<const char*>(xs) + (sx << 16);
            f32x4 acc0 = {0.f, 0.f, 0.f, 0.f};
            f32x4 acc1 = {0.f, 0.f, 0.f, 0.f};
            #pragma unroll
            for (int t = 0; t < 8; ++t) {
                bf16x8 a0 = *reinterpret_cast<const bf16x8*>(xbp + aaddr[2 * t]);
                bf16x8 a1 = *reinterpret_cast<const bf16x8*>(xbp + aaddr[2 * t + 1]);
                acc0 = __builtin_amdgcn_mfma_f32_16x16x32_bf16(a0, bfrag[2 * t],     acc0, 0, 0, 0);
                acc1 = __builtin_amdgcn_mfma_f32_16x16x32_bf16(a1, bfrag[2 * t + 1], acc1, 0, 0, 0);
            }
            int trow = tok0 + (sx << 4) + (g << 2);
            size_t ob = (size_t)trow * 2048 + (r << 4) + n;
            #pragma unroll
            for (int p = 0; p < 4; ++p)
                out[ob + (size_t)p * 2048] = acc0[p] + acc1[p] + fb;
        }
    }
}

extern "C" void kernel_launch(void* const* d_in, const int* in_sizes, int n_in,
                              void* d_out, int out_size, void* d_ws, size_t ws_size,
                              hipStream_t stream) {
    const float* x      = (const float*)d_in[0];
    const float* values = (const float*)d_in[1];
    const int*   cols   = (const int*)d_in[2];
    const float* bias   = (const float*)d_in[3];
    float*       out    = (float*)d_out;

    const size_t xb_bytes = (size_t)TOKS * FEAT * 2;          // 8 MiB
    const size_t vb_bytes = (size_t)NR * KB * 256 * 2;        // 2 MiB
    const int grid = (TOKS / TT) * (NR / RB);                 // 256

    if (ws_size >= xb_bytes + vb_bytes) {
        unsigned short* xbuf = (unsigned short*)d_ws;
        unsigned short* vbuf = (unsigned short*)((char*)d_ws + xb_bytes);
        prep_kernel<<<2048 + 512, 256, 0, stream>>>(x, values, xbuf, vbuf);
        bsp3<<<grid, 1024, 0, stream>>>(xbuf, vbuf, cols, bias, out);
    } else {
        bsp_fb<<<grid, 1024, 0, stream>>>(x, values, cols, bias, out);
    }
}

// Round 4
// 25.188 us; speedup vs baseline: 1.0028x; 1.0028x over previous
//
#include <hip/hip_runtime.h>
#include <hip/hip_bf16.h>

#define TOKS 2048
#define FEAT 2048
#define NR   128
#define KB   32
#define RB   32
#define TT   32

typedef __attribute__((ext_vector_type(8))) short bf16x8;
typedef __attribute__((ext_vector_type(4))) float f32x4;

__device__ __forceinline__ unsigned short f2bf(float f) {
    unsigned u = __builtin_bit_cast(unsigned, f);
    u += 0x7FFFu + ((u >> 16) & 1u);
    return (unsigned short)(u >> 16);
}

__device__ __forceinline__ bf16x8 pack8(float4 a, float4 b) {
    bf16x8 r;
    r[0] = (short)f2bf(a.x); r[1] = (short)f2bf(a.y);
    r[2] = (short)f2bf(a.z); r[3] = (short)f2bf(a.w);
    r[4] = (short)f2bf(b.x); r[5] = (short)f2bf(b.y);
    r[6] = (short)f2bf(b.z); r[7] = (short)f2bf(b.w);
    return r;
}

__global__ __launch_bounds__(256) void cvt_values_kernel(const float* __restrict__ v,
                                                         unsigned short* __restrict__ o,
                                                         int n) {
    int i = (blockIdx.x * 256 + threadIdx.x) * 4;
    if (i + 3 < n) {
        float4 f = *reinterpret_cast<const float4*>(v + i);
        ushort4 r;
        r.x = f2bf(f.x); r.y = f2bf(f.y); r.z = f2bf(f.z); r.w = f2bf(f.w);
        *reinterpret_cast<ushort4*>(o + i) = r;
    }
}

// B-fragments for one r: 16 x bf16x8 + LDS gather addresses.
// cols loads are wave-uniform (cb uniform, t literal, q folded via cndmask).
__device__ __forceinline__ void load_r_frags(const unsigned short* __restrict__ vb,
                                             const int* __restrict__ cols,
                                             int r, int q, int n, int h,
                                             int mrow, int axor,
                                             bf16x8* bf, int* aa) {
    int cb = __builtin_amdgcn_readfirstlane(r) * KB;
    const unsigned short* vbl = vb + ((size_t)r << 13) + (q << 8) + (n << 4) + (h << 3);
    #pragma unroll
    for (int t = 0; t < 16; ++t) {
        bf[t] = *reinterpret_cast<const bf16x8*>(vbl + t * 512);
        int c0 = cols[cb + 2 * t];       // uniform -> s_load
        int c1 = cols[cb + 2 * t + 1];   // uniform -> s_load
        int c  = q ? c1 : c0;
        aa[t] = mrow + (((c << 5) + (h << 4)) ^ axor);
    }
}

// 16 MFMAs (one r, one 16-token subtile), two independent chains.
__device__ __forceinline__ f32x4 dot_r(const char* __restrict__ xbp,
                                       const int* aa, const bf16x8* bf) {
    f32x4 a0 = {0.f, 0.f, 0.f, 0.f};
    f32x4 a1 = {0.f, 0.f, 0.f, 0.f};
    #pragma unroll
    for (int t = 0; t < 8; ++t) {
        bf16x8 x0 = *reinterpret_cast<const bf16x8*>(xbp + aa[2 * t]);
        bf16x8 x1 = *reinterpret_cast<const bf16x8*>(xbp + aa[2 * t + 1]);
        a0 = __builtin_amdgcn_mfma_f32_16x16x32_bf16(x0, bf[2 * t],     a0, 0, 0, 0);
        a1 = __builtin_amdgcn_mfma_f32_16x16x32_bf16(x1, bf[2 * t + 1], a1, 0, 0, 0);
    }
    return a0 + a1;
}

__device__ __forceinline__ void store_r(float* __restrict__ out, int tok0, int sx,
                                        int g, int r, int n, float fb, f32x4 acc) {
    int trow = tok0 + (sx << 4) + (g << 2);
    size_t ob = (size_t)trow * 2048 + (r << 4) + n;
    #pragma unroll
    for (int p = 0; p < 4; ++p)
        out[ob + (size_t)p * 2048] = acc[p] + fb;
}

// grid = 64 tg * 4 rg = 256 blocks, 512 threads (8 waves).
// Software-pipelined: stage rows 0-15 | prefetch pair0 frags | barrier |
// ds_write rows 16-31 + compute sx0(pair0) | barrier | sx1(pair0) | pair1.
__global__ __launch_bounds__(512) void bsp4(const float* __restrict__ x,
                                            const unsigned short* __restrict__ vb,
                                            const int* __restrict__ cols,
                                            const float* __restrict__ bias,
                                            float* __restrict__ out) {
    __shared__ __align__(16) unsigned short xs[TT * FEAT];   // 128 KiB

    int bid  = blockIdx.x;
    int xcd  = bid & 7, slot = bid >> 3;
    int tg   = xcd * 8 + (slot >> 2);
    int rg   = slot & 3;
    int tok0 = tg * TT;
    int r0   = rg * RB;
    int tid  = threadIdx.x;
    int wave = tid >> 6;
    int lane = tid & 63;

    int tr = tid >> 8;          // 0..1
    int ch = tid & 255;         // 16B chunk within a 4KB row

    // ---- issue ALL x global loads (both halves) up front ----
    float4 A0[8], B0[8];
    #pragma unroll
    for (int it = 0; it < 8; ++it) {
        const float4* p = reinterpret_cast<const float4*>(
            x + (size_t)(tok0 + it * 2 + tr) * FEAT + ch * 8);
        A0[it] = p[0]; B0[it] = p[1];
    }
    float4 A1[8], B1[8];
    #pragma unroll
    for (int it = 0; it < 8; ++it) {
        const float4* p = reinterpret_cast<const float4*>(
            x + (size_t)(tok0 + 16 + it * 2 + tr) * FEAT + ch * 8);
        A1[it] = p[0]; B1[it] = p[1];
    }

    // ---- convert + ds_write half0 (rows 0-15), swizzled ----
    #pragma unroll
    for (int it = 0; it < 8; ++it) {
        int t = it * 2 + tr;
        int off = (t << 12) + ((ch << 4) ^ ((t & 7) << 4));
        *reinterpret_cast<bf16x8*>(reinterpret_cast<char*>(xs) + off) = pack8(A0[it], B0[it]);
    }
    // ---- convert half1 into packed regs (written after barrier1) ----
    bf16x8 H1[8];
    #pragma unroll
    for (int it = 0; it < 8; ++it) H1[it] = pack8(A1[it], B1[it]);

    int n = lane & 15;
    int g = lane >> 4;
    int h = g & 1;
    int q = g >> 1;
    int mrow = n << 12;
    int axor = (n & 7) << 4;

    // ---- prefetch pair0 fragments under the staging drain ----
    int rA = r0 + wave * 4;
    bf16x8 bfA[16], bfB[16];
    int aaA[16], aaB[16];
    load_r_frags(vb, cols, rA,     q, n, h, mrow, axor, bfA, aaA);
    load_r_frags(vb, cols, rA + 1, q, n, h, mrow, axor, bfB, aaB);
    float fbA = bias[(rA << 4) + n];
    float fbB = bias[((rA + 1) << 4) + n];

    __syncthreads();            // half0 visible (drains vmem + lds)

    // ds_write half1 (upper 64 KiB; disjoint from sx0 reads)
    #pragma unroll
    for (int it = 0; it < 8; ++it) {
        int t = it * 2 + tr + 16;
        int off = (t << 12) + ((ch << 4) ^ ((t & 7) << 4));
        *reinterpret_cast<bf16x8*>(reinterpret_cast<char*>(xs) + off) = H1[it];
    }

    const char* xb0 = reinterpret_cast<const char*>(xs);
    f32x4 sA0 = dot_r(xb0, aaA, bfA);
    f32x4 sB0 = dot_r(xb0, aaB, bfB);

    __syncthreads();            // half1 visible

    const char* xb1 = reinterpret_cast<const char*>(xs) + 65536;
    f32x4 sA1 = dot_r(xb1, aaA, bfA);
    f32x4 sB1 = dot_r(xb1, aaB, bfB);

    store_r(out, tok0, 0, g, rA,     n, fbA, sA0);
    store_r(out, tok0, 1, g, rA,     n, fbA, sA1);
    store_r(out, tok0, 0, g, rA + 1, n, fbB, sB0);
    store_r(out, tok0, 1, g, rA + 1, n, fbB, sB1);

    // ---- pair1 (reuses bfrag/aaddr registers) ----
    int rC = rA + 2;
    load_r_frags(vb, cols, rC,     q, n, h, mrow, axor, bfA, aaA);
    load_r_frags(vb, cols, rC + 1, q, n, h, mrow, axor, bfB, aaB);
    float fbC = bias[(rC << 4) + n];
    float fbD = bias[((rC + 1) << 4) + n];

    f32x4 sC0 = dot_r(xb0, aaA, bfA);
    f32x4 sD0 = dot_r(xb0, aaB, bfB);
    f32x4 sC1 = dot_r(xb1, aaA, bfA);
    f32x4 sD1 = dot_r(xb1, aaB, bfB);

    store_r(out, tok0, 0, g, rC,     n, fbC, sC0);
    store_r(out, tok0, 1, g, rC,     n, fbC, sC1);
    store_r(out, tok0, 0, g, rC + 1, n, fbD, sD0);
    store_r(out, tok0, 1, g, rC + 1, n, fbD, sD1);
}

// ---------------- fallback (small ws): fp32 values direct ----------------
__global__ __launch_bounds__(1024, 4) void bsp_fb(const float* __restrict__ x,
                                                  const float* __restrict__ values,
                                                  const int* __restrict__ cols,
                                                  const float* __restrict__ bias,
                                                  float* __restrict__ out) {
    __shared__ __align__(16) unsigned short xs[TT * FEAT];

    int bid  = blockIdx.x;
    int xcd  = bid & 7, slot = bid >> 3;
    int tg   = xcd * 8 + (slot >> 2);
    int rg   = slot & 3;
    int tok0 = tg * TT;
    int r0   = rg * RB;
    int tid  = threadIdx.x;

    {
        int tr = tid >> 8;
        int ch = tid & 255;
        #pragma unroll 2
        for (int it = 0; it < 8; ++it) {
            int t = it * 4 + tr;
            const float4* p = reinterpret_cast<const float4*>(
                x + (size_t)(tok0 + t) * FEAT + ch * 8);
            float4 a = p[0], b = p[1];
            int off = (t << 12) + ((ch << 4) ^ ((t & 7) << 4));
            *reinterpret_cast<bf16x8*>(reinterpret_cast<char*>(xs) + off) = pack8(a, b);
        }
    }
    __syncthreads();

    int wave = tid >> 6;
    int lane = tid & 63;
    int n = lane & 15;
    int g = lane >> 4;
    int h = g & 1;
    int q = g >> 1;
    int mrow = n << 12;
    int axor = (n & 7) << 4;

    #pragma unroll 1
    for (int rr = 0; rr < 2; ++rr) {
        int r = r0 + wave * 2 + rr;
        int cbase = __builtin_amdgcn_readfirstlane(r) * KB;
        bf16x8 bfrag[16];
        int aaddr[16];
        const float* vfl = values + ((size_t)r << 13) + (q << 8) + (n << 4) + (h << 3);
        #pragma unroll
        for (int t = 0; t < 16; ++t) {
            const float4* pv = reinterpret_cast<const float4*>(vfl + t * 512);
            bfrag[t] = pack8(pv[0], pv[1]);
            int c = cols[cbase + 2 * t + q];
            aaddr[t] = mrow + (((c << 5) + (h << 4)) ^ axor);
        }
        float fb = bias[(r << 4) + n];
        #pragma unroll
        for (int sx = 0; sx < 2; ++sx) {
            const char* xbp = reinterpret_cast<const char*>(xs) + (sx << 16);
            f32x4 acc0 = {0.f, 0.f, 0.f, 0.f};
            f32x4 acc1 = {0.f, 0.f, 0.f, 0.f};
            #pragma unroll
            for (int t = 0; t < 8; ++t) {
                bf16x8 a0 = *reinterpret_cast<const bf16x8*>(xbp + aaddr[2 * t]);
                bf16x8 a1 = *reinterpret_cast<const bf16x8*>(xbp + aaddr[2 * t + 1]);
                acc0 = __builtin_amdgcn_mfma_f32_16x16x32_bf16(a0, bfrag[2 * t],     acc0, 0, 0, 0);
                acc1 = __builtin_amdgcn_mfma_f32_16x16x32_bf16(a1, bfrag[2 * t + 1], acc1, 0, 0, 0);
            }
            int trow = tok0 + (sx << 4) + (g << 2);
            size_t ob = (size_t)trow * 2048 + (r << 4) + n;
            #pragma unroll
            for (int p = 0; p < 4; ++p)
                out[ob + (size_t)p * 2048] = acc0[p] + acc1[p] + fb;
        }
    }
}

extern "C" void kernel_launch(void* const* d_in, const int* in_sizes, int n_in,
                              void* d_out, int out_size, void* d_ws, size_t ws_size,
                              hipStream_t stream) {
    const float* x      = (const float*)d_in[0];
    const float* values = (const float*)d_in[1];
    const int*   cols   = (const int*)d_in[2];
    const float* bias   = (const float*)d_in[3];
    float*       out    = (float*)d_out;

    const int nv = NR * KB * 16 * 16;              // 1,048,576 values elements
    const int grid = (TOKS / TT) * (NR / RB);      // 256

    if (ws_size >= (size_t)nv * sizeof(unsigned short)) {
        unsigned short* vbuf = (unsigned short*)d_ws;
        cvt_values_kernel<<<nv / (256 * 4), 256, 0, stream>>>(values, vbuf, nv);
        bsp4<<<grid, 512, 0, stream>>>(x, vbuf, cols, bias, out);
    } else {
        bsp_fb<<<grid, 1024, 0, stream>>>(x, values, cols, bias, out);
    }
}